// Round 2
// baseline (150.327 us; speedup 1.0000x reference)
//
#include <hip/hip_runtime.h>
#include <cmath>

// SSIM stability loss: 1 - mean(SSIM(x,y)), 11x11 Gaussian (sigma=1.5), zero SAME
// padding, fp32, 32 x 1 x 512 x 512.
//
// Row-streaming band kernel. Block = 256 threads = 256 columns x 32-row band.
// The 42 needed H-rows (band + 2*5 halo) stream through an 11-row LDS chunk
// holding (x,y) interleaved as float2 (one ds_read_b64 fetches both inputs).
// Horizontal 11-tap conv -> 5 channels (x, y, xx, yy, xy) per H-row, stored in
// an 11-deep circular register history; vertical 11-tap conv is a register
// dot-product when a row completes. Chunk size 11 == history depth, so all
// circular indices are compile-time after unrolling only the 11-row inner loop.
// Single dispatch: per-block partial -> fp64 atomicAdd, last block writes out.

#define IMG   512
#define BCOLS 256
#define BROWS 32
#define NH    42          // H rows per band = BROWS + 10
#define CHR   11          // rows per LDS chunk (== history depth)
#define LCOLS 272         // staged cols per row (mult of 4; covers c0-8 .. c0+263)
#define LUNITS 68         // LCOLS / 4
#define NUNITS (CHR * LUNITS)   // 748 float4-units per chunk
#define NBLOCKS 1024
#define NPIX  8388608.0

struct GaussW { float w[11]; };

__global__ __launch_bounds__(256, 4)
void ssim_stream_kernel(const float* __restrict__ x, const float* __restrict__ y,
                        double* __restrict__ acc_ws, unsigned long long* __restrict__ ctr,
                        float* __restrict__ out, GaussW gw) {
    __shared__ float2 tile[CHR][LCOLS];   // (x,y) interleaved; 11*272*8 = 23936 B
    __shared__ float wavesum[4];

    const int tid = threadIdx.x;
    const int c0 = blockIdx.x * BCOLS;
    const int r0 = blockIdx.y * BROWS;
    const size_t img_off = (size_t)blockIdx.z * (IMG * IMG);
    const float* __restrict__ xb = x + img_off;
    const float* __restrict__ yb = y + img_off;

    float4 sxr[3], syr[3];   // staged regs for the next chunk (3 iters x 256 thr >= 748)

    auto load_chunk = [&](int c) {
        #pragma unroll
        for (int it = 0; it < 3; ++it) {
            int idx = tid + it * 256;
            int row = idx / LUNITS;
            int unit = idx - row * LUNITS;
            int gr = r0 - 5 + c * CHR + row;       // global image row
            int gc = c0 - 8 + unit * 4;            // global col of float4 (16B aligned)
            float4 vx = make_float4(0.f, 0.f, 0.f, 0.f);
            float4 vy = vx;
            // gc % 4 == 0, so (unsigned)gc < IMG implies gc+3 <= 511: whole unit in/out.
            if (idx < NUNITS && (unsigned)gr < IMG && (unsigned)gc < IMG) {
                const float* px = xb + (size_t)gr * IMG + gc;
                const float* py = yb + (size_t)gr * IMG + gc;
                vx = *(const float4*)px;
                vy = *(const float4*)py;
            }
            sxr[it] = vx; syr[it] = vy;
        }
    };
    auto store_chunk = [&]() {
        #pragma unroll
        for (int it = 0; it < 3; ++it) {
            int idx = tid + it * 256;
            if (idx < NUNITS) {
                int row = idx / LUNITS;
                int unit = idx - row * LUNITS;
                float2* dst = &tile[row][unit * 4];
                dst[0] = make_float2(sxr[it].x, syr[it].x);
                dst[1] = make_float2(sxr[it].y, syr[it].y);
                dst[2] = make_float2(sxr[it].z, syr[it].z);
                dst[3] = make_float2(sxr[it].w, syr[it].w);
            }
        }
    };

    float hist0[11], hist1[11], hist2[11], hist3[11], hist4[11];  // circular H history
    float lsum = 0.f;
    const float C1 = 1e-4f, C2 = 9e-4f;
    const int ci = tid;   // local output column; taps at tile cols ci+3 .. ci+13

    load_chunk(0);
    store_chunk();
    __syncthreads();

    for (int c = 0; c < 4; ++c) {           // 4 chunks x 11 rows = 44 >= 42
        if (c < 3) load_chunk(c + 1);       // global loads overlap chunk-c compute

        #pragma unroll
        for (int s = 0; s < CHR; ++s) {     // H-row m = 11c + s; hist slot = s
            if (!(c == 3 && s >= 9)) {      // m < 42 (uniform guard)
                // --- horizontal 11-tap conv, 5 channels ---
                float hx = 0.f, hy = 0.f, hxx = 0.f, hyy = 0.f, hxy = 0.f;
                #pragma unroll
                for (int k = 0; k < 11; ++k) {
                    float2 t = tile[s][ci + 3 + k];
                    float wk = gw.w[k];
                    float ta = wk * t.x;
                    float tb = wk * t.y;
                    hx += ta;
                    hy += tb;
                    hxx = fmaf(ta, t.x, hxx);
                    hyy = fmaf(tb, t.y, hyy);
                    hxy = fmaf(ta, t.y, hxy);
                }
                hist0[s] = hx; hist1[s] = hy; hist2[s] = hxx; hist3[s] = hyy; hist4[s] = hxy;

                // --- output row o = m-10 completes now (needs m >= 10) ---
                if (c > 0 || s == 10) {
                    // slot of H row o+j is (s+1+j) % 11  (static per s,j)
                    float v0 = 0.f, v1 = 0.f, v2 = 0.f, v3 = 0.f, v4 = 0.f;
                    #pragma unroll
                    for (int j = 0; j < 11; ++j) {
                        const int sl = (s + 1 + j) % 11;
                        float wj = gw.w[j];
                        v0 = fmaf(wj, hist0[sl], v0);
                        v1 = fmaf(wj, hist1[sl], v1);
                        v2 = fmaf(wj, hist2[sl], v2);
                        v3 = fmaf(wj, hist3[sl], v3);
                        v4 = fmaf(wj, hist4[sl], v4);
                    }
                    float mx = v0, my = v1;
                    float mxx = mx * mx, myy = my * my, mxy = mx * my;
                    float sxx = v2 - mxx, syy = v3 - myy, sxy = v4 - mxy;
                    float num = (2.f * mxy + C1) * (2.f * sxy + C2);
                    float den = (mxx + myy + C1) * (sxx + syy + C2);
                    lsum += num * __builtin_amdgcn_rcpf(den);
                }
            }
        }

        __syncthreads();                    // everyone done reading tile
        if (c < 3) { store_chunk(); __syncthreads(); }
    }

    // ---- reduction: wave shuffle -> LDS -> block partial -> fp64 atomic ----
    #pragma unroll
    for (int off = 32; off > 0; off >>= 1)
        lsum += __shfl_down(lsum, off, 64);
    if ((tid & 63) == 0) wavesum[tid >> 6] = lsum;
    __syncthreads();
    if (tid == 0) {
        float bs = wavesum[0] + wavesum[1] + wavesum[2] + wavesum[3];
        atomicAdd(acc_ws, (double)bs);
        __threadfence();
        unsigned long long old = atomicAdd(ctr, 1ull);
        if (old == (unsigned long long)(NBLOCKS - 1)) {
            __threadfence();
            double total = atomicAdd(acc_ws, 0.0);   // atomic read-modify sees all adds
            out[0] = (float)(1.0 - total / NPIX);
        }
    }
}

extern "C" void kernel_launch(void* const* d_in, const int* in_sizes, int n_in,
                              void* d_out, int out_size, void* d_ws, size_t ws_size,
                              hipStream_t stream) {
    const float* x = (const float*)d_in[0];   // heatmap_clean
    const float* y = (const float*)d_in[1];   // heatmap_adv
    float* out = (float*)d_out;
    double* acc = (double*)d_ws;
    unsigned long long* ctr = (unsigned long long*)((char*)d_ws + 8);

    // zero the 16B of accumulator+counter state (capture-safe async memset)
    hipMemsetAsync(d_ws, 0, 16, stream);

    GaussW gw;
    double g[11], s = 0.0;
    for (int i = 0; i < 11; ++i) { double d = i - 5; g[i] = exp(-(d * d) / 4.5); s += g[i]; }
    for (int i = 0; i < 11; ++i) gw.w[i] = (float)(g[i] / s);

    dim3 grid(IMG / BCOLS, IMG / BROWS, 32);   // (2, 16, 32) = 1024 blocks
    ssim_stream_kernel<<<grid, 256, 0, stream>>>(x, y, acc, ctr, out, gw);
}

// Round 3
// 139.982 us; speedup vs baseline: 1.0739x; 1.0739x over previous
//
#include <hip/hip_runtime.h>
#include <cmath>

// SSIM stability loss: 1 - mean(SSIM(x,y)), 11x11 Gaussian (sigma=1.5), zero SAME
// padding, fp32, 32 x 1 x 512 x 512.
//
// Row-streaming band kernel. Block = 256 threads = 256 columns x 32-row band.
// The 42 needed H-rows (band + 2*5 halo) stream through an 11-row LDS chunk
// holding (x,y) interleaved as float2 (one ds_read_b64 fetches both inputs).
// Horizontal 11-tap conv -> 5 channels (x, y, xx, yy, xy) per H-row, stored in
// an 11-deep circular register history; vertical 11-tap conv is a register
// dot-product when a row completes. Chunk size 11 == history depth, so all
// circular indices are compile-time after unrolling only the 11-row inner loop.
// Single dispatch: per-block partial -> fp64 atomicAdd, last block writes out.
//
// R2 -> R3: __launch_bounds__(256, 4) forced a 64-VGPR cap; the 55-reg vertical
// history spilled to scratch (WRITE_SIZE 38 MB, VALUBusy 36%). Plain
// __launch_bounds__(256) lets the ~110-150 live regs stay in VGPRs.

#define IMG   512
#define BCOLS 256
#define BROWS 32
#define NH    42          // H rows per band = BROWS + 10
#define CHR   11          // rows per LDS chunk (== history depth)
#define LCOLS 272         // staged cols per row (mult of 4; covers c0-8 .. c0+263)
#define LUNITS 68         // LCOLS / 4
#define NUNITS (CHR * LUNITS)   // 748 float4-units per chunk
#define NBLOCKS 1024
#define NPIX  8388608.0

struct GaussW { float w[11]; };

__global__ __launch_bounds__(256)
void ssim_stream_kernel(const float* __restrict__ x, const float* __restrict__ y,
                        double* __restrict__ acc_ws, unsigned long long* __restrict__ ctr,
                        float* __restrict__ out, GaussW gw) {
    __shared__ float2 tile[CHR][LCOLS];   // (x,y) interleaved; 11*272*8 = 23936 B
    __shared__ float wavesum[4];

    const int tid = threadIdx.x;
    const int c0 = blockIdx.x * BCOLS;
    const int r0 = blockIdx.y * BROWS;
    const size_t img_off = (size_t)blockIdx.z * (IMG * IMG);
    const float* __restrict__ xb = x + img_off;
    const float* __restrict__ yb = y + img_off;

    float4 sxr[3], syr[3];   // staged regs for the next chunk (3 iters x 256 thr >= 748)

    auto load_chunk = [&](int c) {
        #pragma unroll
        for (int it = 0; it < 3; ++it) {
            int idx = tid + it * 256;
            int row = idx / LUNITS;
            int unit = idx - row * LUNITS;
            int gr = r0 - 5 + c * CHR + row;       // global image row
            int gc = c0 - 8 + unit * 4;            // global col of float4 (16B aligned)
            float4 vx = make_float4(0.f, 0.f, 0.f, 0.f);
            float4 vy = vx;
            // gc % 4 == 0, so (unsigned)gc < IMG implies gc+3 <= 511: whole unit in/out.
            if (idx < NUNITS && (unsigned)gr < IMG && (unsigned)gc < IMG) {
                const float* px = xb + (size_t)gr * IMG + gc;
                const float* py = yb + (size_t)gr * IMG + gc;
                vx = *(const float4*)px;
                vy = *(const float4*)py;
            }
            sxr[it] = vx; syr[it] = vy;
        }
    };
    auto store_chunk = [&]() {
        #pragma unroll
        for (int it = 0; it < 3; ++it) {
            int idx = tid + it * 256;
            if (idx < NUNITS) {
                int row = idx / LUNITS;
                int unit = idx - row * LUNITS;
                float2* dst = &tile[row][unit * 4];
                dst[0] = make_float2(sxr[it].x, syr[it].x);
                dst[1] = make_float2(sxr[it].y, syr[it].y);
                dst[2] = make_float2(sxr[it].z, syr[it].z);
                dst[3] = make_float2(sxr[it].w, syr[it].w);
            }
        }
    };

    float hist0[11], hist1[11], hist2[11], hist3[11], hist4[11];  // circular H history
    float lsum = 0.f;
    const float C1 = 1e-4f, C2 = 9e-4f;
    const int ci = tid;   // local output column; taps at tile cols ci+3 .. ci+13

    load_chunk(0);
    store_chunk();
    __syncthreads();

    for (int c = 0; c < 4; ++c) {           // 4 chunks x 11 rows = 44 >= 42
        if (c < 3) load_chunk(c + 1);       // global loads overlap chunk-c compute

        #pragma unroll
        for (int s = 0; s < CHR; ++s) {     // H-row m = 11c + s; hist slot = s
            if (!(c == 3 && s >= 9)) {      // m < 42 (uniform guard)
                // --- horizontal 11-tap conv, 5 channels ---
                float hx = 0.f, hy = 0.f, hxx = 0.f, hyy = 0.f, hxy = 0.f;
                #pragma unroll
                for (int k = 0; k < 11; ++k) {
                    float2 t = tile[s][ci + 3 + k];
                    float wk = gw.w[k];
                    float ta = wk * t.x;
                    float tb = wk * t.y;
                    hx += ta;
                    hy += tb;
                    hxx = fmaf(ta, t.x, hxx);
                    hyy = fmaf(tb, t.y, hyy);
                    hxy = fmaf(ta, t.y, hxy);
                }
                hist0[s] = hx; hist1[s] = hy; hist2[s] = hxx; hist3[s] = hyy; hist4[s] = hxy;

                // --- output row o = m-10 completes now (needs m >= 10) ---
                if (c > 0 || s == 10) {
                    // slot of H row o+j is (s+1+j) % 11  (static per s,j)
                    float v0 = 0.f, v1 = 0.f, v2 = 0.f, v3 = 0.f, v4 = 0.f;
                    #pragma unroll
                    for (int j = 0; j < 11; ++j) {
                        const int sl = (s + 1 + j) % 11;
                        float wj = gw.w[j];
                        v0 = fmaf(wj, hist0[sl], v0);
                        v1 = fmaf(wj, hist1[sl], v1);
                        v2 = fmaf(wj, hist2[sl], v2);
                        v3 = fmaf(wj, hist3[sl], v3);
                        v4 = fmaf(wj, hist4[sl], v4);
                    }
                    float mx = v0, my = v1;
                    float mxx = mx * mx, myy = my * my, mxy = mx * my;
                    float sxx = v2 - mxx, syy = v3 - myy, sxy = v4 - mxy;
                    float num = (2.f * mxy + C1) * (2.f * sxy + C2);
                    float den = (mxx + myy + C1) * (sxx + syy + C2);
                    lsum += num * __builtin_amdgcn_rcpf(den);
                }
            }
        }

        __syncthreads();                    // everyone done reading tile
        if (c < 3) { store_chunk(); __syncthreads(); }
    }

    // ---- reduction: wave shuffle -> LDS -> block partial -> fp64 atomic ----
    #pragma unroll
    for (int off = 32; off > 0; off >>= 1)
        lsum += __shfl_down(lsum, off, 64);
    if ((tid & 63) == 0) wavesum[tid >> 6] = lsum;
    __syncthreads();
    if (tid == 0) {
        float bs = wavesum[0] + wavesum[1] + wavesum[2] + wavesum[3];
        atomicAdd(acc_ws, (double)bs);
        __threadfence();
        unsigned long long old = atomicAdd(ctr, 1ull);
        if (old == (unsigned long long)(NBLOCKS - 1)) {
            __threadfence();
            double total = atomicAdd(acc_ws, 0.0);   // atomic read-modify sees all adds
            out[0] = (float)(1.0 - total / NPIX);
        }
    }
}

extern "C" void kernel_launch(void* const* d_in, const int* in_sizes, int n_in,
                              void* d_out, int out_size, void* d_ws, size_t ws_size,
                              hipStream_t stream) {
    const float* x = (const float*)d_in[0];   // heatmap_clean
    const float* y = (const float*)d_in[1];   // heatmap_adv
    float* out = (float*)d_out;
    double* acc = (double*)d_ws;
    unsigned long long* ctr = (unsigned long long*)((char*)d_ws + 8);

    // zero the 16B of accumulator+counter state (capture-safe async memset)
    hipMemsetAsync(d_ws, 0, 16, stream);

    GaussW gw;
    double g[11], s = 0.0;
    for (int i = 0; i < 11; ++i) { double d = i - 5; g[i] = exp(-(d * d) / 4.5); s += g[i]; }
    for (int i = 0; i < 11; ++i) gw.w[i] = (float)(g[i] / s);

    dim3 grid(IMG / BCOLS, IMG / BROWS, 32);   // (2, 16, 32) = 1024 blocks
    ssim_stream_kernel<<<grid, 256, 0, stream>>>(x, y, acc, ctr, out, gw);
}

// Round 4
// 139.896 us; speedup vs baseline: 1.0746x; 1.0006x over previous
//
#include <hip/hip_runtime.h>
#include <cmath>

// SSIM stability loss: 1 - mean(SSIM(x,y)), 11x11 Gaussian (sigma=1.5), zero SAME
// padding, fp32, 32 x 1 x 512 x 512.
//
// Row-streaming band kernel. Block = 256 threads = 256 columns x 32-row band.
// 42 H-rows (band + 2*5 halo) stream through an 11-row LDS chunk holding (x,y)
// interleaved as float2 (one ds_read_b64 per tap fetches both inputs).
// Horizontal 11-tap conv -> 5 channels per H-row into an 11-deep circular
// register history; vertical 11-tap conv is a register dot-product on row
// completion. Single dispatch; per-block partial -> fp64 atomicAdd.
//
// R3 -> R4: packed fp32 math. CDNA4 issues wave64 VALU at 2 cyc/instr; the
// (x,y) / (hx,hy) / (hxx,hyy) channel pairs map onto v_pk_fma_f32 /
// v_pk_mul_f32 (2 floats per instr): horizontal 7->4 instr/tap, vertical
// 5->3 instr/tap (~40% VALU issue removed). Chunk loop no longer fully
// unrolled (I-cache: ~6.5K instr body -> ~1.6K); hist slot indices depend
// only on (s,j), still compile-time.

#define IMG   512
#define BCOLS 256
#define BROWS 32
#define NH    42          // H rows per band = BROWS + 10
#define CHR   11          // rows per LDS chunk (== history depth)
#define LCOLS 272         // staged cols per row (mult of 4; covers c0-8 .. c0+263)
#define LUNITS 68         // LCOLS / 4
#define NUNITS (CHR * LUNITS)   // 748 float4-units per chunk
#define NBLOCKS 1024
#define NPIX  8388608.0

typedef float v2f __attribute__((ext_vector_type(2)));

struct GaussW { float w[11]; };

__global__ __launch_bounds__(256)
void ssim_stream_kernel(const float* __restrict__ x, const float* __restrict__ y,
                        double* __restrict__ acc_ws, unsigned long long* __restrict__ ctr,
                        float* __restrict__ out, GaussW gw) {
    __shared__ v2f tile[CHR][LCOLS];      // (x,y) interleaved; 11*272*8 = 23936 B
    __shared__ float wavesum[4];

    const int tid = threadIdx.x;
    const int c0 = blockIdx.x * BCOLS;
    const int r0 = blockIdx.y * BROWS;
    const size_t img_off = (size_t)blockIdx.z * (IMG * IMG);
    const float* __restrict__ xb = x + img_off;
    const float* __restrict__ yb = y + img_off;

    // broadcast weights into packed pairs once
    v2f wp[11];
    #pragma unroll
    for (int k = 0; k < 11; ++k) { wp[k][0] = gw.w[k]; wp[k][1] = gw.w[k]; }

    float4 sxr[3], syr[3];   // staged regs for the next chunk (3 iters x 256 thr >= 748)

    auto load_chunk = [&](int c) {
        #pragma unroll
        for (int it = 0; it < 3; ++it) {
            int idx = tid + it * 256;
            int row = idx / LUNITS;
            int unit = idx - row * LUNITS;
            int gr = r0 - 5 + c * CHR + row;       // global image row
            int gc = c0 - 8 + unit * 4;            // global col of float4 (16B aligned)
            float4 vx = make_float4(0.f, 0.f, 0.f, 0.f);
            float4 vy = vx;
            // gc % 4 == 0, so (unsigned)gc < IMG implies gc+3 <= 511: whole unit in/out.
            if (idx < NUNITS && (unsigned)gr < IMG && (unsigned)gc < IMG) {
                const float* px = xb + (size_t)gr * IMG + gc;
                const float* py = yb + (size_t)gr * IMG + gc;
                vx = *(const float4*)px;
                vy = *(const float4*)py;
            }
            sxr[it] = vx; syr[it] = vy;
        }
    };
    auto store_chunk = [&]() {
        #pragma unroll
        for (int it = 0; it < 3; ++it) {
            int idx = tid + it * 256;
            if (idx < NUNITS) {
                int row = idx / LUNITS;
                int unit = idx - row * LUNITS;
                v2f* dst = &tile[row][unit * 4];
                dst[0] = (v2f){sxr[it].x, syr[it].x};
                dst[1] = (v2f){sxr[it].y, syr[it].y};
                dst[2] = (v2f){sxr[it].z, syr[it].z};
                dst[3] = (v2f){sxr[it].w, syr[it].w};
            }
        }
    };

    v2f hist01[11];    // (hx, hy)
    v2f hist23[11];    // (hxx, hyy)
    float hist4[11];   // hxy
    float lsum = 0.f;
    const float C1 = 1e-4f, C2 = 9e-4f;
    const int ci = tid;   // local output column; taps at tile cols ci+3 .. ci+13

    load_chunk(0);
    store_chunk();
    __syncthreads();

    #pragma unroll 1
    for (int c = 0; c < 4; ++c) {           // 4 chunks x 11 rows = 44 >= 42
        if (c < 3) load_chunk(c + 1);       // global loads overlap chunk-c compute

        #pragma unroll
        for (int s = 0; s < CHR; ++s) {     // H-row m = 11c + s; hist slot = s
            if (!(c == 3 && s >= 9)) {      // m < 42 (wave-uniform guard)
                // --- horizontal 11-tap conv, packed channels ---
                v2f h01 = (v2f){0.f, 0.f};
                v2f h23 = (v2f){0.f, 0.f};
                float h4 = 0.f;
                #pragma unroll
                for (int k = 0; k < 11; ++k) {
                    v2f t = tile[s][ci + 3 + k];
                    v2f tt = wp[k] * t;                               // v_pk_mul_f32
                    h01 = __builtin_elementwise_fma(wp[k], t, h01);   // v_pk_fma_f32
                    h23 = __builtin_elementwise_fma(tt, t, h23);      // v_pk_fma_f32
                    h4 = fmaf(tt[0], t[1], h4);                       // wk*x*y
                }
                hist01[s] = h01; hist23[s] = h23; hist4[s] = h4;

                // --- output row o = m-10 completes now (needs m >= 10) ---
                if (c > 0 || s == 10) {
                    // slot of H row o+j is (s+1+j) % 11 (static per s,j)
                    v2f a01 = (v2f){0.f, 0.f};
                    v2f a23 = (v2f){0.f, 0.f};
                    float a4 = 0.f;
                    #pragma unroll
                    for (int j = 0; j < 11; ++j) {
                        const int sl = (s + 1 + j) % 11;
                        a01 = __builtin_elementwise_fma(wp[j], hist01[sl], a01);
                        a23 = __builtin_elementwise_fma(wp[j], hist23[sl], a23);
                        a4 = fmaf(wp[j][0], hist4[sl], a4);
                    }
                    float mx = a01[0], my = a01[1];
                    float mxx = mx * mx, myy = my * my, mxy = mx * my;
                    float sxx = a23[0] - mxx, syy = a23[1] - myy, sxy = a4 - mxy;
                    float num = (2.f * mxy + C1) * (2.f * sxy + C2);
                    float den = (mxx + myy + C1) * (sxx + syy + C2);
                    lsum += num * __builtin_amdgcn_rcpf(den);
                }
            }
        }

        __syncthreads();                    // everyone done reading tile
        if (c < 3) { store_chunk(); __syncthreads(); }
    }

    // ---- reduction: wave shuffle -> LDS -> block partial -> fp64 atomic ----
    #pragma unroll
    for (int off = 32; off > 0; off >>= 1)
        lsum += __shfl_down(lsum, off, 64);
    if ((tid & 63) == 0) wavesum[tid >> 6] = lsum;
    __syncthreads();
    if (tid == 0) {
        float bs = wavesum[0] + wavesum[1] + wavesum[2] + wavesum[3];
        atomicAdd(acc_ws, (double)bs);
        __threadfence();
        unsigned long long old = atomicAdd(ctr, 1ull);
        if (old == (unsigned long long)(NBLOCKS - 1)) {
            __threadfence();
            double total = atomicAdd(acc_ws, 0.0);   // atomic RMW sees all prior adds
            out[0] = (float)(1.0 - total / NPIX);
        }
    }
}

extern "C" void kernel_launch(void* const* d_in, const int* in_sizes, int n_in,
                              void* d_out, int out_size, void* d_ws, size_t ws_size,
                              hipStream_t stream) {
    const float* x = (const float*)d_in[0];   // heatmap_clean
    const float* y = (const float*)d_in[1];   // heatmap_adv
    float* out = (float*)d_out;
    double* acc = (double*)d_ws;
    unsigned long long* ctr = (unsigned long long*)((char*)d_ws + 8);

    // zero the 16B of accumulator+counter state (capture-safe async memset)
    hipMemsetAsync(d_ws, 0, 16, stream);

    GaussW gw;
    double g[11], s = 0.0;
    for (int i = 0; i < 11; ++i) { double d = i - 5; g[i] = exp(-(d * d) / 4.5); s += g[i]; }
    for (int i = 0; i < 11; ++i) gw.w[i] = (float)(g[i] / s);

    dim3 grid(IMG / BCOLS, IMG / BROWS, 32);   // (2, 16, 32) = 1024 blocks
    ssim_stream_kernel<<<grid, 256, 0, stream>>>(x, y, acc, ctr, out, gw);
}